// Round 2
// baseline (4978.554 us; speedup 1.0000x reference)
//
#include <hip/hip_runtime.h>
#include <cmath>

typedef __bf16 bf16x8 __attribute__((ext_vector_type(8)));
typedef float floatx4 __attribute__((ext_vector_type(4)));
typedef unsigned short u16;

#define B_ 16
#define T_ 512
#define D_ 512
#define H_ 1024
#define G_ 2048  // 2H

// ---------------- cast fp32 -> bf16 (RNE) ----------------
__global__ void cast_f32_bf16(const float* __restrict__ src, u16* __restrict__ dst, int n) {
  int i = blockIdx.x * blockDim.x + threadIdx.x;
  int stride = gridDim.x * blockDim.x;
  for (; i < n; i += stride) {
    __bf16 b = (__bf16)src[i];
    dst[i] = *reinterpret_cast<u16*>(&b);
  }
}

// ---------------- w = x @ W^T  (bf16 MFMA, fp32 out) ----------------
// Output layout: w[t][b][2H]  (t-major so the scan reads a contiguous 128 KB/step).
// grid: 512 blocks x 256 thr. Block handles 16 consecutive (b,t) rows x 2048 cols, K=512.
__launch_bounds__(256, 1)
__global__ void gemm_xW(const u16* __restrict__ xb, const u16* __restrict__ Wb,
                        float* __restrict__ w) {
  const int lane = threadIdx.x & 63;
  const int wv = threadIdx.x >> 6;
  const int rt0 = blockIdx.x * 16;          // rows r = b*T + t, 16 consecutive, same b
  const int bidx = rt0 >> 9;                // batch index (T=512)
  const int t0 = rt0 & 511;                 // base t for m=0
  const int am = lane & 15;
  const int kq = lane >> 4;

  // A fragments: 16 k-steps of 32 -> K=512, register resident
  bf16x8 af[16];
  {
    const u16* xrow = xb + (size_t)(rt0 + am) * D_ + kq * 8;
#pragma unroll
    for (int kk = 0; kk < 16; ++kk)
      af[kk] = *reinterpret_cast<const bf16x8*>(xrow + kk * 32);
  }

#pragma unroll 1
  for (int nt = 0; nt < 32; ++nt) {
    const int n0 = wv * 512 + nt * 16;
    floatx4 acc = {0.f, 0.f, 0.f, 0.f};
    const u16* wrow = Wb + (size_t)(n0 + am) * D_ + kq * 8;
#pragma unroll
    for (int kk = 0; kk < 16; ++kk) {
      bf16x8 bfr = *reinterpret_cast<const bf16x8*>(wrow + kk * 32);
      acc = __builtin_amdgcn_mfma_f32_16x16x32_bf16(af[kk], bfr, acc, 0, 0, 0);
    }
    // C/D: col = lane&15 (n), row = kq*4 + reg (m). Out row' = (t0+m)*16 + bidx.
#pragma unroll
    for (int i = 0; i < 4; ++i) {
      int m = kq * 4 + i;
      w[(size_t)((t0 + m) * 16 + bidx) * G_ + n0 + am] = acc[i];
    }
  }
}

// ---------------- in-place LayerNorm over rows of 2048 ----------------
__launch_bounds__(256, 1)
__global__ void layernorm_rows(float* __restrict__ w, const float* __restrict__ gamma,
                               const float* __restrict__ beta) {
  float* r = w + (size_t)blockIdx.x * G_;
  float v[8];
  float s = 0.f, ss = 0.f;
#pragma unroll
  for (int i = 0; i < 8; ++i) {
    v[i] = r[threadIdx.x + i * 256];
    s += v[i];
    ss += v[i] * v[i];
  }
#pragma unroll
  for (int d = 1; d < 64; d <<= 1) {
    s += __shfl_xor(s, d, 64);
    ss += __shfl_xor(ss, d, 64);
  }
  __shared__ float ls[4], lss[4];
  const int wv = threadIdx.x >> 6;
  if ((threadIdx.x & 63) == 0) { ls[wv] = s; lss[wv] = ss; }
  __syncthreads();
  float S = ls[0] + ls[1] + ls[2] + ls[3];
  float SS = lss[0] + lss[1] + lss[2] + lss[3];
  float mu = S * (1.f / 2048.f);
  float var = SS * (1.f / 2048.f) - mu * mu;
  float rs = rsqrtf(var + 1e-5f);
#pragma unroll
  for (int i = 0; i < 8; ++i) {
    int g = threadIdx.x + i * 256;
    r[g] = (v[i] - mu) * rs * gamma[g] + beta[g];
  }
}

// ---------------- fast grid barrier: per-block epoch flags ----------------
// flags[blk*16] is block blk's epoch (monotonic; flags memset to 0 by host).
// 64B stride -> each poller owns a cacheline.
__device__ __forceinline__ void gbar(unsigned* flags, int ep, int tid, int blk) {
  __threadfence();            // release: drain stores, make visible device-wide
  __syncthreads();            // all threads of this block have released
  if (tid == 0)
    __hip_atomic_store(&flags[blk * 16], (unsigned)ep, __ATOMIC_RELEASE,
                       __HIP_MEMORY_SCOPE_AGENT);
  if (tid < 32) {
    while (__hip_atomic_load(&flags[tid * 16], __ATOMIC_RELAXED,
                             __HIP_MEMORY_SCOPE_AGENT) < (unsigned)ep) {
    }
  }
  __syncthreads();
  __threadfence();            // acquire: invalidate stale cached h
}

// ---------------- persistent LiGRU scan (custom barrier) ----------------
// 32 blocks x 256 thr. Block blk owns h cols [blk*32, blk*32+32).
// Waves 0,1: a-rows; waves 2,3: z-rows. U frags register-resident (128 VGPR).
__launch_bounds__(256, 1)
__global__ void ligru_scan(const float* __restrict__ w, const u16* __restrict__ Ub,
                           const float* __restrict__ h0, float* __restrict__ out,
                           u16* __restrict__ hbuf, unsigned* __restrict__ flags) {
  const int blk = blockIdx.x;
  const int tid = threadIdx.x;
  const int lane = tid & 63;
  const int wv = tid >> 6;
  const int am = lane & 15;
  const int kq = lane >> 4;
  const int j0 = blk * 32;

  __shared__ float lds_g[4][16][16];    // raw gate tiles [wave][batch][col]
  __shared__ float lds_hown[16][32];    // fp32 master copy of owned h slice

  const int n0g = (wv < 2) ? (j0 + wv * 16) : (H_ + j0 + (wv - 2) * 16);

  // preload U fragments: wave's 16 gate rows, K=1024 -> 32 k-steps
  bf16x8 uf[32];
  {
    const u16* urow = Ub + (size_t)(n0g + am) * H_ + kq * 8;
#pragma unroll
    for (int kk = 0; kk < 32; ++kk)
      uf[kk] = *reinterpret_cast<const bf16x8*>(urow + kk * 32);
  }

  // init h state (h0 broadcast over batch) into buffer 0 + LDS master
  for (int idx = tid; idx < 512; idx += 256) {
    int b = idx >> 5, jj = idx & 31;
    float hv = h0[j0 + jj];
    lds_hown[b][jj] = hv;
    __bf16 hb = (__bf16)hv;
    hbuf[b * H_ + j0 + jj] = *reinterpret_cast<u16*>(&hb);
  }

  int ep = 1;
  gbar(flags, ep, tid, blk); ++ep;

  // preload w for t=0 (layout [T][B][G])
  float wreg[4];
#pragma unroll
  for (int i = 0; i < 4; ++i)
    wreg[i] = w[(size_t)(kq * 4 + i) * G_ + n0g + am];

  for (int t = 0; t < T_; ++t) {
    const u16* cur = hbuf + (t & 1) * (B_ * H_);
    u16* nxt = hbuf + ((t + 1) & 1) * (B_ * H_);

    // gates tile: D[m=batch][n=gate row], K=1024, A direct from global (L1-reuse)
    floatx4 acc0 = {0, 0, 0, 0}, acc1 = {0, 0, 0, 0};
    floatx4 acc2 = {0, 0, 0, 0}, acc3 = {0, 0, 0, 0};
    {
      const u16* hb = cur + am * H_ + kq * 8;
#pragma unroll
      for (int kk = 0; kk < 8; ++kk) {
        bf16x8 a0 = *reinterpret_cast<const bf16x8*>(hb + (kk + 0) * 32);
        bf16x8 a1 = *reinterpret_cast<const bf16x8*>(hb + (kk + 8) * 32);
        bf16x8 a2 = *reinterpret_cast<const bf16x8*>(hb + (kk + 16) * 32);
        bf16x8 a3 = *reinterpret_cast<const bf16x8*>(hb + (kk + 24) * 32);
        acc0 = __builtin_amdgcn_mfma_f32_16x16x32_bf16(a0, uf[kk + 0], acc0, 0, 0, 0);
        acc1 = __builtin_amdgcn_mfma_f32_16x16x32_bf16(a1, uf[kk + 8], acc1, 0, 0, 0);
        acc2 = __builtin_amdgcn_mfma_f32_16x16x32_bf16(a2, uf[kk + 16], acc2, 0, 0, 0);
        acc3 = __builtin_amdgcn_mfma_f32_16x16x32_bf16(a3, uf[kk + 24], acc3, 0, 0, 0);
      }
    }
    floatx4 acc = (acc0 + acc1) + (acc2 + acc3);

    // prefetch w for t+1 (independent of h; drains under the pre-barrier vmcnt)
    float wnext[4];
    {
      int tn = (t + 1 < T_) ? (t + 1) : t;
      const float* wt = w + (size_t)tn * B_ * G_;
#pragma unroll
      for (int i = 0; i < 4; ++i)
        wnext[i] = wt[(size_t)(kq * 4 + i) * G_ + n0g + am];
    }

    // add w bias, park raw gates in LDS for the a/z pairing exchange
#pragma unroll
    for (int i = 0; i < 4; ++i)
      lds_g[wv][kq * 4 + i][am] = acc[i] + wreg[i];
    __syncthreads();

    // h update: pair a (waves 0/1) with z (waves 2/3)
#pragma unroll
    for (int r = 0; r < 2; ++r) {
      int idx = tid + r * 256;
      int b = idx >> 5, jj = idx & 31;
      float a = lds_g[jj >> 4][b][jj & 15];
      float z = lds_g[2 + (jj >> 4)][b][jj & 15];
      float zs = 1.f / (1.f + __expf(-z));
      float hc = fmaxf(a, 0.f);
      float hold = lds_hown[b][jj];
      float hn = zs * hold + (1.f - zs) * hc;
      lds_hown[b][jj] = hn;
      out[((size_t)b * T_ + t) * H_ + j0 + jj] = hn;
      __bf16 hb16 = (__bf16)hn;
      nxt[b * H_ + j0 + jj] = *reinterpret_cast<u16*>(&hb16);
    }

#pragma unroll
    for (int i = 0; i < 4; ++i) wreg[i] = wnext[i];

    gbar(flags, ep, tid, blk); ++ep;
  }
}

// ---------------- host ----------------
extern "C" void kernel_launch(void* const* d_in, const int* in_sizes, int n_in,
                              void* d_out, int out_size, void* d_ws, size_t ws_size,
                              hipStream_t stream) {
  (void)in_sizes; (void)n_in; (void)out_size; (void)ws_size;
  const float* x = (const float*)d_in[0];
  const float* Ww = (const float*)d_in[1];
  const float* Uw = (const float*)d_in[2];
  const float* gamma = (const float*)d_in[3];
  const float* beta = (const float*)d_in[4];
  const float* h0 = (const float*)d_in[5];
  float* out = (float*)d_out;

  char* p = (char*)d_ws;
  u16* xb = (u16*)p;      p += (size_t)8192 * 512 * 2;   // 8 MB
  u16* Wb = (u16*)p;      p += (size_t)2048 * 512 * 2;   // 2 MB
  u16* Ub = (u16*)p;      p += (size_t)2048 * 1024 * 2;  // 4 MB
  float* w = (float*)p;   p += (size_t)8192 * 2048 * 4;  // 64 MB  [T][B][G]
  u16* hbuf = (u16*)p;    p += (size_t)2 * B_ * H_ * 2;  // 64 KB (double buffer)
  unsigned* flags = (unsigned*)p; p += 32 * 64;          // 2 KB barrier flags

  hipMemsetAsync(flags, 0, 32 * 64, stream);
  cast_f32_bf16<<<512, 256, 0, stream>>>(x, xb, 8192 * 512);
  cast_f32_bf16<<<256, 256, 0, stream>>>(Ww, Wb, 2048 * 512);
  cast_f32_bf16<<<256, 256, 0, stream>>>(Uw, Ub, 2048 * 1024);
  gemm_xW<<<512, 256, 0, stream>>>(xb, Wb, w);
  layernorm_rows<<<8192, 256, 0, stream>>>(w, gamma, beta);

  const float* wc = w;
  const u16* Ubc = Ub;
  void* args[6] = { (void*)&wc, (void*)&Ubc, (void*)&h0, (void*)&out,
                    (void*)&hbuf, (void*)&flags };
  hipLaunchCooperativeKernel((void*)ligru_scan, dim3(32), dim3(256), args, 0, stream);
}

// Round 4
// 3364.407 us; speedup vs baseline: 1.4798x; 1.4798x over previous
//
#include <hip/hip_runtime.h>
#include <cmath>

typedef __bf16 bf16x8 __attribute__((ext_vector_type(8)));
typedef float floatx4 __attribute__((ext_vector_type(4)));
typedef unsigned short u16;

#define B_ 16
#define T_ 512
#define D_ 512
#define H_ 1024
#define G_ 2048  // 2H

// ---------------- cast fp32 -> bf16 (RNE) ----------------
__global__ void cast_f32_bf16(const float* __restrict__ src, u16* __restrict__ dst, int n) {
  int i = blockIdx.x * blockDim.x + threadIdx.x;
  int stride = gridDim.x * blockDim.x;
  for (; i < n; i += stride) {
    __bf16 b = (__bf16)src[i];
    dst[i] = *reinterpret_cast<u16*>(&b);
  }
}

// ---------------- w = x @ W^T  (bf16 MFMA, fp32 out), layout w[t][b][2H] ----------------
__launch_bounds__(256, 1)
__global__ void gemm_xW(const u16* __restrict__ xb, const u16* __restrict__ Wb,
                        float* __restrict__ w) {
  const int lane = threadIdx.x & 63;
  const int wv = threadIdx.x >> 6;
  const int rt0 = blockIdx.x * 16;          // rows r = b*T + t, 16 consecutive, same b
  const int bidx = rt0 >> 9;                // batch index (T=512)
  const int t0 = rt0 & 511;                 // base t for m=0
  const int am = lane & 15;
  const int kq = lane >> 4;

  bf16x8 af[16];
  {
    const u16* xrow = xb + (size_t)(rt0 + am) * D_ + kq * 8;
#pragma unroll
    for (int kk = 0; kk < 16; ++kk)
      af[kk] = *reinterpret_cast<const bf16x8*>(xrow + kk * 32);
  }

#pragma unroll 1
  for (int nt = 0; nt < 32; ++nt) {
    const int n0 = wv * 512 + nt * 16;
    floatx4 acc = {0.f, 0.f, 0.f, 0.f};
    const u16* wrow = Wb + (size_t)(n0 + am) * D_ + kq * 8;
#pragma unroll
    for (int kk = 0; kk < 16; ++kk) {
      bf16x8 bfr = *reinterpret_cast<const bf16x8*>(wrow + kk * 32);
      acc = __builtin_amdgcn_mfma_f32_16x16x32_bf16(af[kk], bfr, acc, 0, 0, 0);
    }
#pragma unroll
    for (int i = 0; i < 4; ++i) {
      int m = kq * 4 + i;
      w[(size_t)((t0 + m) * 16 + bidx) * G_ + n0 + am] = acc[i];
    }
  }
}

// ---------------- in-place LayerNorm over rows of 2048 ----------------
__launch_bounds__(256, 1)
__global__ void layernorm_rows(float* __restrict__ w, const float* __restrict__ gamma,
                               const float* __restrict__ beta) {
  float* r = w + (size_t)blockIdx.x * G_;
  float v[8];
  float s = 0.f, ss = 0.f;
#pragma unroll
  for (int i = 0; i < 8; ++i) {
    v[i] = r[threadIdx.x + i * 256];
    s += v[i];
    ss += v[i] * v[i];
  }
#pragma unroll
  for (int d = 1; d < 64; d <<= 1) {
    s += __shfl_xor(s, d, 64);
    ss += __shfl_xor(ss, d, 64);
  }
  __shared__ float ls[4], lss[4];
  const int wv = threadIdx.x >> 6;
  if ((threadIdx.x & 63) == 0) { ls[wv] = s; lss[wv] = ss; }
  __syncthreads();
  float S = ls[0] + ls[1] + ls[2] + ls[3];
  float SS = lss[0] + lss[1] + lss[2] + lss[3];
  float mu = S * (1.f / 2048.f);
  float var = SS * (1.f / 2048.f) - mu * mu;
  float rs = rsqrtf(var + 1e-5f);
#pragma unroll
  for (int i = 0; i < 8; ++i) {
    int g = threadIdx.x + i * 256;
    r[g] = (v[i] - mu) * rs * gamma[g] + beta[g];
  }
}

// ---------------- persistent LiGRU scan: producer-flag dataflow ----------------
// 32 blocks x 256 thr. Block blk owns h cols [blk*32, blk*32+32).
// h_t lives in hbuf[t&1] (plain bf16 stores). Block publishes via RELEASE store
// of flags[blk]=t+2 after its slice is drained; consumers ACQUIRE-poll all 32
// flags >= t+1, then plain-load h. No mutual barrier; skew <= 1 by induction.
__launch_bounds__(256, 1)
__global__ void ligru_scan(const float* __restrict__ w, const u16* __restrict__ Ub,
                           const float* __restrict__ h0, float* __restrict__ out,
                           u16* __restrict__ hbuf, unsigned* __restrict__ flags) {
  const int tid = threadIdx.x;
  const int lane = tid & 63;
  const int wv = tid >> 6;
  const int am = lane & 15;
  const int kq = lane >> 4;
  const int blk = blockIdx.x;
  const int j0 = blk * 32;

  __shared__ float lds_g[4][16][16];    // raw gate tiles [wave][batch][col]
  __shared__ float lds_hown[16][32];    // fp32 master copy of owned h slice

  const int n0g = (wv < 2) ? (j0 + wv * 16) : (H_ + j0 + (wv - 2) * 16);

  // preload U fragments: wave's 16 gate rows, K=1024 -> 32 k-steps
  bf16x8 uf[32];
  {
    const u16* urow = Ub + (size_t)(n0g + am) * H_ + kq * 8;
#pragma unroll
    for (int kk = 0; kk < 32; ++kk)
      uf[kk] = *reinterpret_cast<const bf16x8*>(urow + kk * 32);
  }

  // preload w for t=0 (layout [T][B][G])
  float wreg[4];
#pragma unroll
  for (int i = 0; i < 4; ++i)
    wreg[i] = w[(size_t)(kq * 4 + i) * G_ + n0g + am];

  // init: own slice of h_0 -> buf0 (plain stores), fp32 master in LDS
#pragma unroll
  for (int r = 0; r < 2; ++r) {
    int idx = tid + r * 256;
    int b = idx >> 5, jj = idx & 31;
    float hv = h0[j0 + jj];
    lds_hown[b][jj] = hv;
    __bf16 hb = (__bf16)hv;
    hbuf[b * H_ + j0 + jj] = *reinterpret_cast<u16*>(&hb);
  }
  __syncthreads();  // drain init stores (vmcnt(0) per wave)
  if (tid == 0)
    __hip_atomic_store(&flags[blk * 16], 1u, __ATOMIC_RELEASE,
                       __HIP_MEMORY_SCOPE_AGENT);

  for (int t = 0; t < T_; ++t) {
    const u16* cur = hbuf + (t & 1) * (B_ * H_);
    u16* nxt = hbuf + ((t + 1) & 1) * (B_ * H_);
    const unsigned want = (unsigned)(t + 1);

    // ---- wait for all producers of h_t (acquire => L1/L2 inv on success) ----
    if (tid < 32) {
      unsigned cnt = 0;
      while (__hip_atomic_load(&flags[tid * 16], __ATOMIC_ACQUIRE,
                               __HIP_MEMORY_SCOPE_AGENT) < want) {
        if (++cnt > (1u << 22)) break;  // safety valve: never hang the queue
      }
    }
    __syncthreads();

    // ---- gates tile: D[m=batch][n=gate row], K=1024, 4 ILP chains ----
    floatx4 acc0 = {0, 0, 0, 0}, acc1 = {0, 0, 0, 0};
    floatx4 acc2 = {0, 0, 0, 0}, acc3 = {0, 0, 0, 0};
    {
      const u16* hb = cur + am * H_ + kq * 8;
#pragma unroll
      for (int kk = 0; kk < 8; ++kk) {
        bf16x8 a0 = *reinterpret_cast<const bf16x8*>(hb + (kk + 0) * 32);
        bf16x8 a1 = *reinterpret_cast<const bf16x8*>(hb + (kk + 8) * 32);
        bf16x8 a2 = *reinterpret_cast<const bf16x8*>(hb + (kk + 16) * 32);
        bf16x8 a3 = *reinterpret_cast<const bf16x8*>(hb + (kk + 24) * 32);
        acc0 = __builtin_amdgcn_mfma_f32_16x16x32_bf16(a0, uf[kk + 0], acc0, 0, 0, 0);
        acc1 = __builtin_amdgcn_mfma_f32_16x16x32_bf16(a1, uf[kk + 8], acc1, 0, 0, 0);
        acc2 = __builtin_amdgcn_mfma_f32_16x16x32_bf16(a2, uf[kk + 16], acc2, 0, 0, 0);
        acc3 = __builtin_amdgcn_mfma_f32_16x16x32_bf16(a3, uf[kk + 24], acc3, 0, 0, 0);
      }
    }
    floatx4 acc = (acc0 + acc1) + (acc2 + acc3);

    // prefetch w for t+1 (off the dependence chain)
    float wnext[4];
    {
      int tn = (t + 1 < T_) ? (t + 1) : t;
      const float* wt = w + (size_t)tn * B_ * G_;
#pragma unroll
      for (int i = 0; i < 4; ++i)
        wnext[i] = wt[(size_t)(kq * 4 + i) * G_ + n0g + am];
    }

    // park w-biased gates in LDS for the a/z pairing exchange
#pragma unroll
    for (int i = 0; i < 4; ++i)
      lds_g[wv][kq * 4 + i][am] = acc[i] + wreg[i];
    __syncthreads();

    // ---- h update: thread handles (b, 2 cols); publish slice FIRST ----
    const int ub = tid >> 4;          // batch 0..15
    const int cp = tid & 15;          // col-pair 0..15
    float hn0, hn1;
    {
      int jj = 2 * cp;
      float a0 = lds_g[jj >> 4][ub][jj & 15];
      float z0 = lds_g[2 + (jj >> 4)][ub][jj & 15];
      float a1 = lds_g[(jj + 1) >> 4][ub][(jj + 1) & 15];
      float z1 = lds_g[2 + ((jj + 1) >> 4)][ub][(jj + 1) & 15];
      float zs0 = 1.f / (1.f + __expf(-z0));
      float zs1 = 1.f / (1.f + __expf(-z1));
      hn0 = zs0 * lds_hown[ub][jj] + (1.f - zs0) * fmaxf(a0, 0.f);
      hn1 = zs1 * lds_hown[ub][jj + 1] + (1.f - zs1) * fmaxf(a1, 0.f);
      lds_hown[ub][jj] = hn0;
      lds_hown[ub][jj + 1] = hn1;
      __bf16 b0 = (__bf16)hn0, b1 = (__bf16)hn1;
      unsigned pk = ((unsigned)*reinterpret_cast<u16*>(&b1) << 16) |
                    (unsigned)*reinterpret_cast<u16*>(&b0);
      *reinterpret_cast<unsigned*>(&nxt[ub * H_ + j0 + jj]) = pk;
    }
    __syncthreads();  // drain slice stores (vmcnt(0) per wave before barrier)
    if (tid == 0)
      __hip_atomic_store(&flags[blk * 16], want + 1u, __ATOMIC_RELEASE,
                         __HIP_MEMORY_SCOPE_AGENT);

    // out stores off the critical path
    {
      int jj = 2 * cp;
      float2 o = make_float2(hn0, hn1);
      *reinterpret_cast<float2*>(&out[((size_t)ub * T_ + t) * H_ + j0 + jj]) = o;
    }

#pragma unroll
    for (int i = 0; i < 4; ++i) wreg[i] = wnext[i];
  }
}

// ---------------- host ----------------
extern "C" void kernel_launch(void* const* d_in, const int* in_sizes, int n_in,
                              void* d_out, int out_size, void* d_ws, size_t ws_size,
                              hipStream_t stream) {
  (void)in_sizes; (void)n_in; (void)out_size; (void)ws_size;
  const float* x = (const float*)d_in[0];
  const float* Ww = (const float*)d_in[1];
  const float* Uw = (const float*)d_in[2];
  const float* gamma = (const float*)d_in[3];
  const float* beta = (const float*)d_in[4];
  const float* h0 = (const float*)d_in[5];
  float* out = (float*)d_out;

  char* p = (char*)d_ws;
  u16* xb = (u16*)p;      p += (size_t)8192 * 512 * 2;   // 8 MB
  u16* Wb = (u16*)p;      p += (size_t)2048 * 512 * 2;   // 2 MB
  u16* Ub = (u16*)p;      p += (size_t)2048 * 1024 * 2;  // 4 MB
  float* w = (float*)p;   p += (size_t)8192 * 2048 * 4;  // 64 MB  [T][B][G]
  u16* hbuf = (u16*)p;    p += (size_t)2 * B_ * H_ * 2;  // 64 KB (double buffer)
  unsigned* flags = (unsigned*)p; p += 32 * 64;          // 2 KB flag lines

  hipMemsetAsync(flags, 0, 32 * 64, stream);  // tags start below 1
  cast_f32_bf16<<<512, 256, 0, stream>>>(x, xb, 8192 * 512);
  cast_f32_bf16<<<256, 256, 0, stream>>>(Ww, Wb, 2048 * 512);
  cast_f32_bf16<<<256, 256, 0, stream>>>(Uw, Ub, 2048 * 1024);
  gemm_xW<<<512, 256, 0, stream>>>(xb, Wb, w);
  layernorm_rows<<<8192, 256, 0, stream>>>(w, gamma, beta);

  const float* wc = w;
  const u16* Ubc = Ub;
  void* args[6] = { (void*)&wc, (void*)&Ubc, (void*)&h0, (void*)&out,
                    (void*)&hbuf, (void*)&flags };
  hipLaunchCooperativeKernel((void*)ligru_scan, dim3(32), dim3(256), args, 0, stream);
}